// Round 1
// baseline (292.664 us; speedup 1.0000x reference)
//
#include <hip/hip_runtime.h>
#include <math.h>

constexpr int NSEG = 16;
constexpr int CC   = 768;   // channels
constexpr int PP   = 197;   // patches
constexpr int NH   = 12;    // heads
constexpr int HD   = 64;    // head dim
constexpr int NT   = 512;   // total rows = B*NSEG
constexpr float LN_EPS = 1e-5f;

// ---------------- shift + layernorm (one block per row) ----------------
__global__ void shift_ln_kernel(const float* __restrict__ x,
                                const float* __restrict__ w1,
                                const float* __restrict__ g,
                                const float* __restrict__ b,
                                float* __restrict__ s_shift,
                                float* __restrict__ t_ln) {
    int r   = blockIdx.x;        // 0..511  (r = batch*16 + seg)
    int seg = r & (NSEG - 1);
    int tid = threadIdx.x;       // 256 threads, 3 elems each
    __shared__ float red[256];

    float vals[3];
    float local = 0.f;
    #pragma unroll
    for (int i = 0; i < 3; ++i) {
        int c = tid + i * 256;
        float v = x[(size_t)r * PP * CC + c];
        if (seg > 0) v += w1[c] * x[(size_t)(r - 1) * PP * CC + c];
        vals[i] = v;
        local += v;
    }
    red[tid] = local; __syncthreads();
    for (int off = 128; off > 0; off >>= 1) {
        if (tid < off) red[tid] += red[tid + off];
        __syncthreads();
    }
    float mu = red[0] * (1.0f / CC);
    __syncthreads();

    float lv = 0.f;
    #pragma unroll
    for (int i = 0; i < 3; ++i) { float d = vals[i] - mu; lv += d * d; }
    red[tid] = lv; __syncthreads();
    for (int off = 128; off > 0; off >>= 1) {
        if (tid < off) red[tid] += red[tid + off];
        __syncthreads();
    }
    float rstd = rsqrtf(red[0] * (1.0f / CC) + LN_EPS);

    #pragma unroll
    for (int i = 0; i < 3; ++i) {
        int c = tid + i * 256;
        s_shift[(size_t)r * CC + c] = vals[i];
        t_ln[(size_t)r * CC + c]    = (vals[i] - mu) * rstd * g[c] + b[c];
    }
}

// ---------------- simple tiled fp32 GEMM:  C = A(MxK) @ B(KxN) + bias (+res) ----------------
template<bool ADD_RES>
__global__ void gemm_kernel(const float* __restrict__ A,
                            const float* __restrict__ B,
                            const float* __restrict__ bias,
                            const float* __restrict__ res,   // MxN, stride N
                            float* __restrict__ Cout,
                            int M, int N, int K,
                            size_t out_row_stride) {
    __shared__ float As[16][16];
    __shared__ float Bs[16][17];
    int tx = threadIdx.x, ty = threadIdx.y;
    int row = blockIdx.y * 16 + ty;
    int col = blockIdx.x * 16 + tx;
    float acc = 0.f;
    for (int k0 = 0; k0 < K; k0 += 16) {
        As[ty][tx] = A[(size_t)row * K + k0 + tx];
        Bs[ty][tx] = B[(size_t)(k0 + ty) * N + col];
        __syncthreads();
        #pragma unroll
        for (int kk = 0; kk < 16; ++kk) acc += As[ty][kk] * Bs[kk][tx];
        __syncthreads();
    }
    acc += bias[col];
    if (ADD_RES) acc += res[(size_t)row * N + col];
    Cout[(size_t)row * out_row_stride + col] = acc;
}

// ---------------- attention over 16 segments, one block per (batch, head) ----------------
__global__ void attn_kernel(const float* __restrict__ q,
                            const float* __restrict__ k,
                            const float* __restrict__ v,
                            float* __restrict__ ctx) {
    int bh = blockIdx.x;           // 0..383
    int bb = bh / NH;              // batch 0..31
    int h  = bh % NH;
    int tid = threadIdx.x;         // 256

    __shared__ float qs[16][HD], ks[16][HD], vs[16][HD];
    __shared__ float sc[16][17];
    __shared__ float rsum[16];

    for (int i = tid; i < 16 * HD; i += 256) {
        int t = i >> 6, d = i & 63;
        size_t gidx = (size_t)(bb * NSEG + t) * CC + h * HD + d;
        qs[t][d] = q[gidx];
        ks[t][d] = k[gidx];
        vs[t][d] = v[gidx];
    }
    __syncthreads();

    {   // 256 threads -> one score each (16x16)
        int t = tid >> 4, s = tid & 15;
        float acc = 0.f;
        #pragma unroll
        for (int d = 0; d < HD; ++d) acc += qs[t][d] * ks[s][d];
        sc[t][s] = acc * 0.125f;   // 1/sqrt(64)
    }
    __syncthreads();

    if (tid < 16) {
        float m = -1e30f;
        #pragma unroll
        for (int s = 0; s < 16; ++s) m = fmaxf(m, sc[tid][s]);
        float sum = 0.f;
        #pragma unroll
        for (int s = 0; s < 16; ++s) { float e = __expf(sc[tid][s] - m); sc[tid][s] = e; sum += e; }
        rsum[tid] = sum;
    }
    __syncthreads();

    for (int i = tid; i < 16 * HD; i += 256) {
        int t = i >> 6, d = i & 63;
        float acc = 0.f;
        #pragma unroll
        for (int s = 0; s < 16; ++s) acc += sc[t][s] * vs[s][d];
        ctx[(size_t)(bb * NSEG + t) * CC + h * HD + d] = acc / rsum[t];
    }
}

extern "C" void kernel_launch(void* const* d_in, const int* in_sizes, int n_in,
                              void* d_out, int out_size, void* d_ws, size_t ws_size,
                              hipStream_t stream) {
    const float* x    = (const float*)d_in[0];
    const float* w1   = (const float*)d_in[1];
    const float* ln_g = (const float*)d_in[2];
    const float* ln_b = (const float*)d_in[3];
    const float* Wq   = (const float*)d_in[4];
    const float* bq   = (const float*)d_in[5];
    const float* Wk   = (const float*)d_in[6];
    const float* bk   = (const float*)d_in[7];
    const float* Wv   = (const float*)d_in[8];
    const float* bv   = (const float*)d_in[9];
    const float* Wo   = (const float*)d_in[10];
    const float* bo   = (const float*)d_in[11];
    float* out = (float*)d_out;

    float* ws      = (float*)d_ws;
    float* s_shift = ws;                     // 512*768
    float* t_ln    = s_shift + NT * CC;
    float* qb      = t_ln    + NT * CC;
    float* kb      = qb      + NT * CC;
    float* vb      = kb      + NT * CC;
    float* ctx     = vb      + NT * CC;      // total 6 * 512*768 * 4B = 9.4 MB

    // bulk pass-through copy x -> out (p=0 rows overwritten by final GEMM below)
    hipMemcpyAsync(out, x, (size_t)NT * PP * CC * sizeof(float),
                   hipMemcpyDeviceToDevice, stream);

    shift_ln_kernel<<<NT, 256, 0, stream>>>(x, w1, ln_g, ln_b, s_shift, t_ln);

    dim3 thr(16, 16);
    dim3 grid(CC / 16, NT / 16);
    gemm_kernel<false><<<grid, thr, 0, stream>>>(t_ln, Wq, bq, nullptr, qb, NT, CC, CC, CC);
    gemm_kernel<false><<<grid, thr, 0, stream>>>(t_ln, Wk, bk, nullptr, kb, NT, CC, CC, CC);
    gemm_kernel<false><<<grid, thr, 0, stream>>>(t_ln, Wv, bv, nullptr, vb, NT, CC, CC, CC);

    attn_kernel<<<32 * NH, 256, 0, stream>>>(qb, kb, vb, ctx);

    // final projection + bias + residual, scattered straight into out[p=0]
    gemm_kernel<true><<<grid, thr, 0, stream>>>(ctx, Wo, bo, s_shift, out,
                                                NT, CC, CC, (size_t)PP * CC);
}

// Round 2
// 159.733 us; speedup vs baseline: 1.8322x; 1.8322x over previous
//
#include <hip/hip_runtime.h>
#include <math.h>

typedef __attribute__((ext_vector_type(8))) short short8;
typedef __attribute__((ext_vector_type(4))) float f32x4;
typedef __attribute__((ext_vector_type(4))) unsigned short us4;

constexpr int NSEG = 16;
constexpr int CC   = 768;
constexpr int PP   = 197;
constexpr int NH   = 12;
constexpr int HD   = 64;
constexpr int NT   = 512;
constexpr int MN   = NT * CC;          // 393216
constexpr float LN_EPS = 1e-5f;

// pass-through copy geometry, in float4 units (p>=1 rows of every token)
constexpr unsigned CPT  = 196 * CC / 4;          // 37632 float4 per token
constexpr unsigned TOK4 = PP * CC / 4;           // 37824
constexpr unsigned ROW4 = CC / 4;                // 192 (skip p=0 row)
constexpr unsigned W4TOT = (unsigned)NT * CPT;   // 19267584

__device__ inline unsigned short f2bf(float f) {
    unsigned u = __float_as_uint(f);
    u += 0x7fffu + ((u >> 16) & 1u);
    return (unsigned short)(u >> 16);
}

__device__ inline void copy_slice(const float* __restrict__ x, float* __restrict__ out,
                                  unsigned start, unsigned end,
                                  unsigned gthread, unsigned nthreads) {
    const float4* __restrict__ x4 = (const float4*)x;
    float4* __restrict__ o4 = (float4*)out;
    for (unsigned i = start + gthread; i < end; i += nthreads) {
        unsigned t = i / CPT;                 // magic-mul div by constant
        unsigned w = i - t * CPT;
        unsigned idx = t * TOK4 + ROW4 + w;
        o4[idx] = x4[idx];
    }
}

// ---------------- 64x64 MFMA bf16 tile, 4 waves, fragments direct from global ----------------
template<bool ADD_RES>
__device__ inline void gemm_tile(const unsigned short* __restrict__ A,   // 512xCC bf16 row-major
                                 const unsigned short* __restrict__ Bt,  // CCxCC bf16, [n][k]
                                 const float* __restrict__ bias,
                                 const float* __restrict__ res,          // 512xCC f32 (if ADD_RES)
                                 float* __restrict__ outp,
                                 int by, int bx, size_t orow) {
    int tid  = threadIdx.x;
    int lane = tid & 63, wv = tid >> 6;
    int wr = wv >> 1, wc = wv & 1;
    int l15 = lane & 15, lh = lane >> 4;
    int m0 = by * 64 + wr * 32;
    int n0 = bx * 64 + wc * 32;
    f32x4 acc[2][2] = {};
    const unsigned short* Ar0 = A  + (size_t)(m0 + l15) * CC + lh * 8;
    const unsigned short* Ar1 = Ar0 + 16 * CC;
    const unsigned short* Br0 = Bt + (size_t)(n0 + l15) * CC + lh * 8;
    const unsigned short* Br1 = Br0 + 16 * CC;
    #pragma unroll 4
    for (int k0 = 0; k0 < CC; k0 += 32) {
        short8 a0 = *(const short8*)(Ar0 + k0);
        short8 a1 = *(const short8*)(Ar1 + k0);
        short8 b0 = *(const short8*)(Br0 + k0);
        short8 b1 = *(const short8*)(Br1 + k0);
        acc[0][0] = __builtin_amdgcn_mfma_f32_16x16x32_bf16(a0, b0, acc[0][0], 0, 0, 0);
        acc[0][1] = __builtin_amdgcn_mfma_f32_16x16x32_bf16(a0, b1, acc[0][1], 0, 0, 0);
        acc[1][0] = __builtin_amdgcn_mfma_f32_16x16x32_bf16(a1, b0, acc[1][0], 0, 0, 0);
        acc[1][1] = __builtin_amdgcn_mfma_f32_16x16x32_bf16(a1, b1, acc[1][1], 0, 0, 0);
    }
    #pragma unroll
    for (int mf = 0; mf < 2; ++mf)
        #pragma unroll
        for (int nf = 0; nf < 2; ++nf)
            #pragma unroll
            for (int r = 0; r < 4; ++r) {
                int row = m0 + mf * 16 + lh * 4 + r;       // D: row=(lane>>4)*4+reg
                int col = n0 + nf * 16 + l15;              //    col=lane&15
                float v = acc[mf][nf][r] + bias[col];
                if (ADD_RES) v += res[(size_t)row * CC + col];
                outp[(size_t)row * orow + col] = v;
            }
}

// ================= K1: shift+LN (512) | weight cvt+transpose (2304) | copy (768) =================
constexpr int K1_LN = NT, K1_CVT = 2304, K1_CPY = 768;
__global__ __launch_bounds__(256) void k1(const float* __restrict__ x, const float* __restrict__ w1,
        const float* __restrict__ g, const float* __restrict__ bln,
        const float* __restrict__ Wq, const float* __restrict__ Wk,
        const float* __restrict__ Wv, const float* __restrict__ Wo,
        float* __restrict__ s_shift, unsigned short* __restrict__ tln,
        unsigned short* __restrict__ wt, float* __restrict__ out,
        unsigned cstart, unsigned cend) {
    __shared__ float smem[32 * 33];
    int bid = blockIdx.x, tid = threadIdx.x;
    if (bid < K1_LN) {
        int r = bid, seg = r & (NSEG - 1);
        float vals[3]; float local = 0.f;
        #pragma unroll
        for (int i = 0; i < 3; ++i) {
            int c = tid + i * 256;
            float v = x[(size_t)r * PP * CC + c];
            if (seg > 0) v += w1[c] * x[(size_t)(r - 1) * PP * CC + c];
            vals[i] = v; local += v;
        }
        smem[tid] = local; __syncthreads();
        for (int off = 128; off > 0; off >>= 1) {
            if (tid < off) smem[tid] += smem[tid + off];
            __syncthreads();
        }
        float mu = smem[0] * (1.0f / CC); __syncthreads();
        float lv = 0.f;
        #pragma unroll
        for (int i = 0; i < 3; ++i) { float d = vals[i] - mu; lv += d * d; }
        smem[tid] = lv; __syncthreads();
        for (int off = 128; off > 0; off >>= 1) {
            if (tid < off) smem[tid] += smem[tid + off];
            __syncthreads();
        }
        float rstd = rsqrtf(smem[0] * (1.0f / CC) + LN_EPS);
        #pragma unroll
        for (int i = 0; i < 3; ++i) {
            int c = tid + i * 256;
            s_shift[(size_t)r * CC + c] = vals[i];
            tln[(size_t)r * CC + c] = f2bf((vals[i] - mu) * rstd * g[c] + bln[c]);
        }
    } else if (bid < K1_LN + K1_CVT) {
        int idx = bid - K1_LN;
        int mat = idx / 576, tile = idx % 576;
        int tr = tile / 24, tc = tile % 24;
        const float* W = mat == 0 ? Wq : mat == 1 ? Wk : mat == 2 ? Wv : Wo;
        int lr = tid >> 3, lc = (tid & 7) * 4;
        float4 v = *(const float4*)(W + (size_t)(tr * 32 + lr) * CC + tc * 32 + lc);
        smem[lr * 33 + lc + 0] = v.x; smem[lr * 33 + lc + 1] = v.y;
        smem[lr * 33 + lc + 2] = v.z; smem[lr * 33 + lc + 3] = v.w;
        __syncthreads();
        int ln_ = tid >> 3, kc = (tid & 7) * 4;
        us4 o;
        #pragma unroll
        for (int j = 0; j < 4; ++j) o[j] = f2bf(smem[(kc + j) * 33 + ln_]);
        *(us4*)(wt + (size_t)mat * CC * CC + (size_t)(tc * 32 + ln_) * CC + tr * 32 + kc) = o;
    } else {
        unsigned cb = bid - (K1_LN + K1_CVT);
        copy_slice(x, out, cstart, cend, cb * 256 + tid, K1_CPY * 256);
    }
}

// ================= K2: QKV MFMA GEMM (288) | copy (1024) =================
constexpr int K2_GEMM = 288, K2_CPY = 1024;
__global__ __launch_bounds__(256) void k2(const unsigned short* __restrict__ tln,
        const unsigned short* __restrict__ wt,
        const float* __restrict__ bq, const float* __restrict__ bk, const float* __restrict__ bv,
        float* __restrict__ qkv,
        const float* __restrict__ x, float* __restrict__ out,
        unsigned cstart, unsigned cend) {
    int bid = blockIdx.x, tid = threadIdx.x;
    if (bid < K2_GEMM) {
        int z = bid / 96, rem = bid % 96;
        int by = rem / 12, bx = rem % 12;
        const unsigned short* Bt = wt + (size_t)z * CC * CC;
        const float* bias = z == 0 ? bq : (z == 1 ? bk : bv);
        float* outp = qkv + (size_t)z * MN;
        gemm_tile<false>(tln, Bt, bias, nullptr, outp, by, bx, CC);
    } else {
        unsigned cb = bid - K2_GEMM;
        copy_slice(x, out, cstart, cend, cb * 256 + tid, K2_CPY * 256);
    }
}

// ================= K3: attention (384) | copy (1024) =================
constexpr int K3_ATT = 32 * NH, K3_CPY = 1024;
__global__ __launch_bounds__(256) void k3(const float* __restrict__ qkv,
        unsigned short* __restrict__ ctxb,
        const float* __restrict__ x, float* __restrict__ out,
        unsigned cstart, unsigned cend) {
    int bid = blockIdx.x, tid = threadIdx.x;
    if (bid < K3_ATT) {
        const float* q = qkv;
        const float* k = qkv + MN;
        const float* v = qkv + 2 * MN;
        int bb = bid / NH, h = bid % NH;
        __shared__ float qs[16][HD], ks[16][HD], vs[16][HD];
        __shared__ float sc[16][17];
        __shared__ float rsum[16];
        for (int i = tid; i < 16 * HD; i += 256) {
            int t = i >> 6, d = i & 63;
            size_t gidx = (size_t)(bb * NSEG + t) * CC + h * HD + d;
            qs[t][d] = q[gidx]; ks[t][d] = k[gidx]; vs[t][d] = v[gidx];
        }
        __syncthreads();
        {
            int t = tid >> 4, s = tid & 15;
            float acc = 0.f;
            #pragma unroll
            for (int d = 0; d < HD; ++d) acc += qs[t][d] * ks[s][d];
            sc[t][s] = acc * 0.125f;
        }
        __syncthreads();
        if (tid < 16) {
            float m = -1e30f;
            #pragma unroll
            for (int s = 0; s < 16; ++s) m = fmaxf(m, sc[tid][s]);
            float sum = 0.f;
            #pragma unroll
            for (int s = 0; s < 16; ++s) { float e = __expf(sc[tid][s] - m); sc[tid][s] = e; sum += e; }
            rsum[tid] = sum;
        }
        __syncthreads();
        for (int i = tid; i < 16 * HD; i += 256) {
            int t = i >> 6, d = i & 63;
            float acc = 0.f;
            #pragma unroll
            for (int s = 0; s < 16; ++s) acc += sc[t][s] * vs[s][d];
            ctxb[(size_t)(bb * NSEG + t) * CC + h * HD + d] = f2bf(acc / rsum[t]);
        }
    } else {
        unsigned cb = bid - K3_ATT;
        copy_slice(x, out, cstart, cend, cb * 256 + tid, K3_CPY * 256);
    }
}

// ================= K4: O-proj GEMM + residual into out[p=0] (96) | copy (1024) =================
constexpr int K4_GEMM = 96, K4_CPY = 1024;
__global__ __launch_bounds__(256) void k4(const unsigned short* __restrict__ ctxb,
        const unsigned short* __restrict__ wto,
        const float* __restrict__ bo, const float* __restrict__ s_shift,
        float* __restrict__ out, const float* __restrict__ x,
        unsigned cstart, unsigned cend) {
    int bid = blockIdx.x, tid = threadIdx.x;
    if (bid < K4_GEMM) {
        int by = bid / 12, bx = bid % 12;
        gemm_tile<true>(ctxb, wto, bo, s_shift, out, by, bx, (size_t)PP * CC);
    } else {
        unsigned cb = bid - K4_GEMM;
        copy_slice(x, out, cstart, cend, cb * 256 + tid, K4_CPY * 256);
    }
}

extern "C" void kernel_launch(void* const* d_in, const int* in_sizes, int n_in,
                              void* d_out, int out_size, void* d_ws, size_t ws_size,
                              hipStream_t stream) {
    const float* x    = (const float*)d_in[0];
    const float* w1   = (const float*)d_in[1];
    const float* ln_g = (const float*)d_in[2];
    const float* ln_b = (const float*)d_in[3];
    const float* Wq   = (const float*)d_in[4];
    const float* bq   = (const float*)d_in[5];
    const float* Wk   = (const float*)d_in[6];
    const float* bk   = (const float*)d_in[7];
    const float* Wv   = (const float*)d_in[8];
    const float* bv   = (const float*)d_in[9];
    const float* Wo   = (const float*)d_in[10];
    const float* bo   = (const float*)d_in[11];
    float* out = (float*)d_out;

    // workspace layout (12.6 MB total)
    float* ws      = (float*)d_ws;
    float* s_shift = ws;                       // MN f32
    float* qkv     = s_shift + MN;             // 3*MN f32
    unsigned short* tln  = (unsigned short*)(qkv + 3 * MN);  // MN bf16
    unsigned short* ctxb = tln + MN;                          // MN bf16
    unsigned short* wt   = ctxb + MN;                         // 4*CC*CC bf16 (q,k,v,o transposed)

    const unsigned s0 = 0, s1 = 5400000u, s2 = 10400000u, s3 = 15400000u, s4 = W4TOT;

    k1<<<K1_LN + K1_CVT + K1_CPY, 256, 0, stream>>>(x, w1, ln_g, ln_b, Wq, Wk, Wv, Wo,
                                                    s_shift, tln, wt, out, s0, s1);
    k2<<<K2_GEMM + K2_CPY, 256, 0, stream>>>(tln, wt, bq, bk, bv, qkv, x, out, s1, s2);
    k3<<<K3_ATT + K3_CPY, 256, 0, stream>>>(qkv, ctxb, x, out, s2, s3);
    k4<<<K4_GEMM + K4_CPY, 256, 0, stream>>>(ctxb, wt + (size_t)3 * CC * CC, bo, s_shift,
                                             out, x, s3, s4);
}